// Round 10
// baseline (101.072 us; speedup 1.0000x reference)
//
#include <hip/hip_runtime.h>
#include <math.h>

#define EMB   300
#define NLOC  10000
#define PP    200
#define NN    1000   // PP * 5
#define BB    128
#define TT    256
#define NSEG  8
#define SEGLEN 32

#define NVBLK 79
#define NNBLK 8
#define NKPAN 40
#define NKSTEP 10
#define ASCALE 16.f
#define BSCALE 64.f
#define OUTSCALE (1.f / 1024.f)

typedef _Float16 f16x8 __attribute__((ext_vector_type(8)));
typedef float    f32x4 __attribute__((ext_vector_type(4)));

typedef const __attribute__((address_space(1))) unsigned int GUI;
typedef __attribute__((address_space(3))) unsigned int LUI;

// ---------------------------------------------------------------------------
// Fused split kernel: fp32 -> (hi f16, lo f16), scaled so residuals stay in
// f16-normal range and all 3 partial products share ONE scale (1024 * a*b):
//   Ah = f16(16a), Al = f16(16a - Ah)   (emb ~ N(0,1))
//   Bh = f16(64b), Bl = f16(64b - Bh)   (diags ~ 0.05*N(0,1))
// Tiled layout, k-innermost per 32-wide k-step (BANK-CONFLICT-FREE reads):
//   A_tiled[vblk][kstep(10)][m(128)][hh(4)][j(8)]   elem = m*32 + hh*8 + j
//   B_tiled[nblk][kstep(10)][n(128)][hh(4)][j(8)]
// A wave's MFMA fragment read is then one contiguous 1024B region.
// ---------------------------------------------------------------------------
__global__ __launch_bounds__(128) void split_ab(const float* __restrict__ emb,
                                                const float* __restrict__ diags,
                                                _Float16* __restrict__ Ah,
                                                _Float16* __restrict__ Al,
                                                _Float16* __restrict__ Bh,
                                                _Float16* __restrict__ Bl) {
    const int m    = threadIdx.x;
    const int bx   = blockIdx.x;
    const int kpan = blockIdx.y;           // 0..39 (8 k-values each)
    const int s    = kpan >> 2;            // k-step (32 k-values)
    const int q    = kpan & 3;             // hh slot within step
    _Float16 hi[8], lo[8];
    if (bx < NVBLK) {
        const int vblk = bx;
        const int v    = vblk * 128 + m;
        const size_t outb = (size_t)vblk * (NKSTEP * 4096) + (size_t)s * 4096 + m * 32 + q * 8;
        #pragma unroll
        for (int j = 0; j < 8; ++j) {
            int e = kpan * 8 + j;
            float x = (v < NLOC && e < EMB) ? emb[(size_t)e * NLOC + v] : 0.f;
            float xs = ASCALE * x;
            _Float16 h = (_Float16)xs;
            hi[j] = h;
            lo[j] = (_Float16)(xs - (float)h);
        }
        *(f16x8*)&Ah[outb] = *(const f16x8*)hi;
        *(f16x8*)&Al[outb] = *(const f16x8*)lo;
    } else {
        const int nblk = bx - NVBLK;
        const int n    = nblk * 128 + m;
        const size_t outb = (size_t)nblk * (NKSTEP * 4096) + (size_t)s * 4096 + m * 32 + q * 8;
        #pragma unroll
        for (int j = 0; j < 8; ++j) {
            int e = kpan * 8 + j;
            float x = (n < NN && e < EMB) ? diags[(size_t)n * EMB + e] : 0.f;
            float xs = BSCALE * x;
            _Float16 h = (_Float16)xs;
            hi[j] = h;
            lo[j] = (_Float16)(xs - (float)h);
        }
        *(f16x8*)&Bh[outb] = *(const f16x8*)hi;
        *(f16x8*)&Bl[outb] = *(const f16x8*)lo;
    }
}

// ---------------------------------------------------------------------------
// LDS-staged MFMA GEMM, 4 blocks/CU. 128x128 tile, 4 waves (2x2).
// Per k-step: stage 32KB via global_load_lds w16 -> barrier -> 16 contiguous
// ds_read_b128 frag reads (conflict-free by layout) + 48 MFMA -> barrier.
// K = 320 in 10 steps. Single f32 accumulator (shared-scale split-f16).
// Epilogue reuses staging LDS (union) for the coalesced transpose stores.
// ---------------------------------------------------------------------------
__global__ __launch_bounds__(256, 4) void gemm_lds(
    const _Float16* __restrict__ Ah, const _Float16* __restrict__ Al,
    const _Float16* __restrict__ Bh, const _Float16* __restrict__ Bl,
    const float* __restrict__ bias, float* __restrict__ trans, int tstr) {
    __shared__ union {
        _Float16 stage[4][4096];   // 32 KB: [Ah,Al,Bh,Bl][128 rows][4 hh][8]
        float    etile[64][132];   // 33.8 KB epilogue transpose tile
    } sh;

    const int tid  = threadIdx.x;

    // bijective chunked swizzle: XCD k owns swz in [79k, 79(k+1))
    const int bid  = blockIdx.x;
    const int swz  = (bid & 7) * 79 + (bid >> 3);
    const int vblk = swz >> 3;   // 8 consecutive swz share vblk -> A reuse in L2
    const int nblk = swz & 7;

    const int lane = tid & 63;
    const int wave = tid >> 6;
    const int wr   = wave >> 1;
    const int wc   = wave & 1;
    const int l15  = lane & 15;
    const int hh   = lane >> 4;  // k-slot (8 wide) within the 32-wide k-step

    const _Float16* gsrc[4] = {
        Ah + (size_t)vblk * (NKSTEP * 4096),
        Al + (size_t)vblk * (NKSTEP * 4096),
        Bh + (size_t)nblk * (NKSTEP * 4096),
        Bl + (size_t)nblk * (NKSTEP * 4096)};

    f32x4 acc[4][4] = {};

    for (int s = 0; s < 10; ++s) {
        // ---- stage 32KB: 8 global_load_lds x 16B per thread (linear) ----
        #pragma unroll
        for (int L = 0; L < 8; ++L) {
            const int arr = L >> 1;                     // compile-time after unroll
            const int off = ((L & 1) * 256 + tid) * 8;  // elem offset in 4096-array
            __builtin_amdgcn_global_load_lds(
                (GUI*)(gsrc[arr] + (size_t)s * 4096 + off),
                (LUI*)&sh.stage[arr][off], 16, 0, 0);
        }
        __syncthreads();

        // ---- compute: 16 contiguous-region ds_read_b128 + 48 MFMA ----
        {
            f16x8 fah[4], fal[4], fbh[4], fbl[4];
            #pragma unroll
            for (int i = 0; i < 4; ++i) {
                const int ra = (wr * 64 + i * 16 + l15) * 32 + hh * 8;
                fah[i] = *(const f16x8*)&sh.stage[0][ra];
                fal[i] = *(const f16x8*)&sh.stage[1][ra];
                const int rb = (wc * 64 + i * 16 + l15) * 32 + hh * 8;
                fbh[i] = *(const f16x8*)&sh.stage[2][rb];
                fbl[i] = *(const f16x8*)&sh.stage[3][rb];
            }
            #pragma unroll
            for (int i = 0; i < 4; ++i)
                #pragma unroll
                for (int j = 0; j < 4; ++j) {
                    acc[i][j] = __builtin_amdgcn_mfma_f32_16x16x32_f16(fah[i], fbh[j], acc[i][j], 0, 0, 0);
                    acc[i][j] = __builtin_amdgcn_mfma_f32_16x16x32_f16(fah[i], fbl[j], acc[i][j], 0, 0, 0);
                    acc[i][j] = __builtin_amdgcn_mfma_f32_16x16x32_f16(fal[i], fbh[j], acc[i][j], 0, 0, 0);
                }
        }
        __syncthreads();   // all reads done before next stage overwrites
    }

    // ---- epilogue: LDS transpose (reuses staging LDS), float4 stores ----
    #pragma unroll 1
    for (int h = 0; h < 2; ++h) {
        __syncthreads();
        if (wr == h) {
            #pragma unroll
            for (int i = 0; i < 4; ++i)
                #pragma unroll
                for (int j = 0; j < 4; ++j)
                    #pragma unroll
                    for (int r = 0; r < 4; ++r)
                        sh.etile[i * 16 + hh * 4 + r][wc * 64 + j * 16 + l15] =
                            acc[i][j][r] * OUTSCALE;
        }
        __syncthreads();
        // 64 rows x 128 floats = 2048 float4; 8 per thread
        #pragma unroll
        for (int it = 0; it < 8; ++it) {
            const int idx = it * 256 + tid;
            const int row = idx >> 5;
            const int c4  = (idx & 31) * 4;
            const int v   = vblk * 128 + h * 64 + row;
            const int n   = nblk * 128 + c4;
            if (v < NLOC && n + 3 < NN) {
                float4 val = *(const float4*)&sh.etile[row][c4];
                const float4 b4 = *(const float4*)&bias[n];
                val.x += b4.x; val.y += b4.y; val.z += b4.z; val.w += b4.w;
                *(float4*)&trans[(size_t)v * tstr + n] = val;
            }
        }
    }
}

// ---------------------------------------------------------------------------
// Fallback fp32 GEMM (round-2 proven, stride 1000) if ws is too small.
// ---------------------------------------------------------------------------
__global__ __launch_bounds__(256) void trans_gemm(const float* __restrict__ emb,
                                                  const float* __restrict__ diags,
                                                  const float* __restrict__ bias,
                                                  float* __restrict__ trans) {
    const int tid = threadIdx.x;
    const int tn  = tid & 15;
    const int tv  = tid >> 4;
    const int v0  = blockIdx.x * 128;
    const int n0  = blockIdx.y * 128;
    __shared__ float As[15][132];
    __shared__ float Bs[15][132];
    float acc[8][8] = {};
    for (int kk = 0; kk < 20; ++kk) {
        const int e0 = kk * 15;
        #pragma unroll
        for (int l = tid; l < 480; l += 256) {
            int k = l >> 5, c = l & 31;
            int v = v0 + c * 4;
            const float* src = emb + (size_t)(e0 + k) * NLOC + v;
            float4 val;
            if (v + 3 < NLOC) val = *(const float4*)src;
            else {
                val.x = (v + 0 < NLOC) ? src[0] : 0.f;
                val.y = (v + 1 < NLOC) ? src[1] : 0.f;
                val.z = (v + 2 < NLOC) ? src[2] : 0.f;
                val.w = (v + 3 < NLOC) ? src[3] : 0.f;
            }
            *(float4*)&As[k][c * 4] = val;
        }
        for (int l = tid; l < 1920; l += 256) {
            int nn = l / 15, k = l - nn * 15;
            int n = n0 + nn;
            Bs[k][nn] = (n < NN) ? diags[n * EMB + e0 + k] : 0.f;
        }
        __syncthreads();
        #pragma unroll
        for (int k = 0; k < 15; ++k) {
            float4 a0 = *(const float4*)&As[k][tv * 4];
            float4 a1 = *(const float4*)&As[k][tv * 4 + 64];
            float4 b0 = *(const float4*)&Bs[k][tn * 4];
            float4 b1 = *(const float4*)&Bs[k][tn * 4 + 64];
            float av[8] = {a0.x, a0.y, a0.z, a0.w, a1.x, a1.y, a1.z, a1.w};
            float bv[8] = {b0.x, b0.y, b0.z, b0.w, b1.x, b1.y, b1.z, b1.w};
            #pragma unroll
            for (int i = 0; i < 8; ++i)
                #pragma unroll
                for (int j = 0; j < 8; ++j)
                    acc[i][j] += av[i] * bv[j];
        }
        __syncthreads();
    }
    #pragma unroll
    for (int i = 0; i < 8; ++i) {
        int v = v0 + (i >> 2) * 64 + tv * 4 + (i & 3);
        if (v >= NLOC) continue;
        #pragma unroll
        for (int jh = 0; jh < 2; ++jh) {
            int n = n0 + jh * 64 + tn * 4;
            if (n + 3 < NN) {
                float4 r;
                r.x = acc[i][jh * 4 + 0] + bias[n + 0];
                r.y = acc[i][jh * 4 + 1] + bias[n + 1];
                r.z = acc[i][jh * 4 + 2] + bias[n + 2];
                r.w = acc[i][jh * 4 + 3] + bias[n + 3];
                *(float4*)&trans[(size_t)v * NN + n] = r;
            } else {
                #pragma unroll
                for (int j = 0; j < 4; ++j)
                    if (n + j < NN)
                        trans[(size_t)v * NN + n + j] = acc[i][jh * 4 + j] + bias[n + j];
            }
        }
    }
}

// ---------------------------------------------------------------------------
// K2: segment-parallel max-plus scan (stride-parameterized)
// ---------------------------------------------------------------------------
__global__ __launch_bounds__(256) void scan_seg(const float* __restrict__ trans,
                                                const float* __restrict__ wildcards,
                                                const int* __restrict__ docs,
                                                const int* __restrict__ doc_lens,
                                                float* __restrict__ partial, int tstr) {
    const int b   = blockIdx.x;
    const int seg = blockIdx.y;
    const int tid = threadIdx.x;
    __shared__ int sdoc[TT];
    sdoc[tid] = docs[b * TT + tid];
    __syncthreads();

    const bool act = tid < PP;
    const int  p   = act ? tid : (PP - 1);
    const int  p5  = p * 5;
    const int  len = doc_lens[b];
    const int  t0  = seg * SEGLEN;
    const int  start = (t0 - 4 > 0) ? t0 - 4 : 0;
    const int  end   = (t0 + SEGLEN < len) ? t0 + SEGLEN : len;

    const float NI = -INFINITY;
    float score = NI;

    if (start < end) {
        const float w0 = wildcards[p5 + 0];
        const float w1 = wildcards[p5 + 1];
        const float w2 = wildcards[p5 + 2];
        const float w3 = wildcards[p5 + 3];
        const float w4 = wildcards[p5 + 4];
        const int e = (p < 50) ? 5 : (p < 100) ? 4 : (p < 150) ? 3 : 2;

        float h1 = NI, h2 = NI, h3 = NI, h4 = NI, h5 = NI;
        const int nt   = end - start;
        const int ntm1 = nt - 1;

        float A[5], B[5], C[5];
#define LOADR(R, idx) { int tt = (idx); tt = (tt < ntm1) ? tt : ntm1;          \
        const float* r_ = trans + (size_t)sdoc[start + tt] * tstr + p5;        \
        R[0] = r_[0]; R[1] = r_[1]; R[2] = r_[2]; R[3] = r_[3]; R[4] = r_[4]; }
#define STEP(R, t) { \
        float u0 = fmaxf(R[0], w0), u1 = fmaxf(R[1], w1), u2 = fmaxf(R[2], w2);\
        float u3 = fmaxf(R[3], w3), u4 = fmaxf(R[4], w4);                      \
        h5 = h4 + u4; h4 = h3 + u3; h3 = h2 + u2; h2 = h1 + u1; h1 = u0;       \
        if ((t) >= t0) {                                                       \
            float endv = (e == 5) ? h5 : (e == 4) ? h4 : (e == 3) ? h3 : h2;   \
            score = fmaxf(score, endv);                                        \
        } }

        LOADR(A, 0); LOADR(B, 1); LOADR(C, 2);
        for (int i = 0; i < nt; i += 3) {
            STEP(A, start + i);
            LOADR(A, i + 3);
            if (i + 1 < nt) { STEP(B, start + i + 1); }
            LOADR(B, i + 4);
            if (i + 2 < nt) { STEP(C, start + i + 2); }
            LOADR(C, i + 5);
        }
#undef LOADR
#undef STEP
    }

    if (act) partial[((size_t)b * NSEG + seg) * PP + p] = score;
}

// ---------------------------------------------------------------------------
// K3: finalize (unchanged, proven)
// ---------------------------------------------------------------------------
__device__ inline float block_sum_bcast(float v, volatile float* red, int tid) {
    #pragma unroll
    for (int o = 32; o > 0; o >>= 1) v += __shfl_down(v, o, 64);
    __syncthreads();
    if ((tid & 63) == 0) red[tid >> 6] = v;
    __syncthreads();
    return red[0] + red[1] + red[2] + red[3];
}

__global__ __launch_bounds__(256) void finalize(const float* __restrict__ partial,
                                                const float* __restrict__ linear_w,
                                                const float* __restrict__ linear_b,
                                                float* __restrict__ out) {
    const int b   = blockIdx.x;
    const int tid = threadIdx.x;
    __shared__ float red[4];

    const bool act = tid < PP;
    const int  p   = act ? tid : (PP - 1);

    float m = -INFINITY;
    #pragma unroll
    for (int s = 0; s < NSEG; ++s)
        m = fmaxf(m, partial[((size_t)b * NSEG + s) * PP + p]);

    float total = block_sum_bcast(act ? m : 0.f, red, tid);
    float mu = total * (1.f / (float)PP);

    int bin = (act && m > mu) ? 1 : 0;
    float c0 = bin ? linear_w[p]      : 0.f;
    float c1 = bin ? linear_w[PP + p] : 0.f;

    float r0 = block_sum_bcast(c0, red, tid);
    float r1 = block_sum_bcast(c1, red, tid);

    if (tid == 0) {
        out[b * 2 + 0] = r0 + linear_b[0];
        out[b * 2 + 1] = r1 + linear_b[1];
    }
}

// ---------------------------------------------------------------------------
extern "C" void kernel_launch(void* const* d_in, const int* in_sizes, int n_in,
                              void* d_out, int out_size, void* d_ws, size_t ws_size,
                              hipStream_t stream) {
    const float* emb    = (const float*)d_in[0];
    const float* diags  = (const float*)d_in[1];
    const float* bias   = (const float*)d_in[2];
    const float* wc     = (const float*)d_in[3];
    const float* lw     = (const float*)d_in[4];
    const float* lb     = (const float*)d_in[5];
    const int*   docs   = (const int*)d_in[6];
    const int*   dlens  = (const int*)d_in[7];
    float*       out    = (float*)d_out;

    const size_t aElems = (size_t)NVBLK * NKSTEP * 4096;  // 3,235,840
    const size_t bElems = (size_t)NNBLK * NKSTEP * 4096;  //   327,680
    const size_t partialElems = (size_t)BB * NSEG * PP;
    const size_t f16Bytes = (2 * aElems + 2 * bElems) * sizeof(_Float16);

    // choose trans stride: 1024 (line-aligned stores) > 1000 > fp32 fallback
    int tstr;
    {
        const size_t need1024 = ((size_t)NLOC * 1024 + partialElems) * 4 + f16Bytes;
        const size_t need1000 = ((size_t)NLOC * 1000 + partialElems) * 4 + f16Bytes;
        if (ws_size >= need1024)       tstr = 1024;
        else if (ws_size >= need1000)  tstr = 1000;
        else                           tstr = 0;   // fp32 fallback
    }

    float* trans   = (float*)d_ws;
    float* partial = trans + (size_t)NLOC * (tstr ? tstr : 1000);
    _Float16* Ah = (_Float16*)(partial + partialElems);
    _Float16* Al = Ah + aElems;
    _Float16* Bh = Al + aElems;
    _Float16* Bl = Bh + bElems;

    if (tstr) {
        split_ab<<<dim3(NVBLK + NNBLK, NKPAN, 1), 128, 0, stream>>>(emb, diags, Ah, Al, Bh, Bl);
        gemm_lds<<<dim3(NVBLK * NNBLK, 1, 1), 256, 0, stream>>>(Ah, Al, Bh, Bl, bias, trans, tstr);
        scan_seg<<<dim3(BB, NSEG, 1), 256, 0, stream>>>(trans, wc, docs, dlens, partial, tstr);
    } else {
        trans_gemm<<<dim3(79, 8, 1), 256, 0, stream>>>(emb, diags, bias, trans);
        scan_seg<<<dim3(BB, NSEG, 1), 256, 0, stream>>>(trans, wc, docs, dlens, partial, 1000);
    }
    finalize<<<BB, 256, 0, stream>>>(partial, lw, lb, out);
}

// Round 11
// 73.488 us; speedup vs baseline: 1.3754x; 1.3754x over previous
//
#include <hip/hip_runtime.h>
#include <math.h>

#define EMB   300
#define NLOC  10000
#define PP    200
#define NN    1000   // PP * 5
#define BB    128
#define TT    256
#define NSEG  8
#define SEGLEN 32

#define NVBLK 79
#define NNBLK 8
#define NKSTEP 10
#define ASCALE 16.f
#define BSCALE 64.f
#define OUTSCALE (1.f / 1024.f)

typedef _Float16 f16x8 __attribute__((ext_vector_type(8)));
typedef float    f32x4 __attribute__((ext_vector_type(4)));

typedef const __attribute__((address_space(1))) unsigned int GUI;
typedef __attribute__((address_space(3))) unsigned int LUI;

// ---------------------------------------------------------------------------
// Fused split kernel: fp32 -> (hi f16, lo f16), scaled so residuals stay in
// f16-normal range and all 3 partial products share ONE scale (1024 * a*b):
//   Ah = f16(16a), Al = f16(16a - Ah)     Bh = f16(64b), Bl = f16(64b - Bh)
//
// READ-ORDER-EXACT tiled layout (bank-conflict-free by construction):
//   A[vblk][s(10)][wr(2)][i(4)][lane(64)][j(8)]
//     holds emb value for v = vblk*128 + wr*64 + i*16 + (lane&15),
//                       k = s*32 + (lane>>4)*8 + j.
//   B[nblk][s][wc][i][lane][j] same with n.
// In the GEMM, wave (wr,wc) fragment-read i is then lane-contiguous 1024B:
// lane l reads chunk l -> ds_read_b128 with zero bank conflicts.
// ---------------------------------------------------------------------------
__global__ __launch_bounds__(128) void split_ab(const float* __restrict__ emb,
                                                const float* __restrict__ diags,
                                                _Float16* __restrict__ Ah,
                                                _Float16* __restrict__ Al,
                                                _Float16* __restrict__ Bh,
                                                _Float16* __restrict__ Bl) {
    const int tid  = threadIdx.x;     // 0..127: wr=tid>>6, i=(tid>>4)&3, l15=tid&15
    const int bx   = blockIdx.x;
    const int kpan = blockIdx.y;      // 0..39: s = kpan>>2, hh = kpan&3
    const int s    = kpan >> 2;
    const int hh   = kpan & 3;
    const int wr   = tid >> 6;
    const int ii   = (tid >> 4) & 3;
    const int l15  = tid & 15;
    const int lane = hh * 16 + l15;
    _Float16 hi[8], lo[8];
    if (bx < NVBLK) {
        const int vblk = bx;
        const int v    = vblk * 128 + tid;   // row index == tid by construction
        const size_t outb = (size_t)vblk * (NKSTEP * 4096) + (size_t)s * 4096
                          + wr * 2048 + ii * 512 + lane * 8;
        #pragma unroll
        for (int j = 0; j < 8; ++j) {
            int e = s * 32 + hh * 8 + j;
            float x = (v < NLOC && e < EMB) ? emb[(size_t)e * NLOC + v] : 0.f;
            float xs = ASCALE * x;
            _Float16 h = (_Float16)xs;
            hi[j] = h;
            lo[j] = (_Float16)(xs - (float)h);
        }
        *(f16x8*)&Ah[outb] = *(const f16x8*)hi;
        *(f16x8*)&Al[outb] = *(const f16x8*)lo;
    } else {
        const int nblk = bx - NVBLK;
        const int n    = nblk * 128 + tid;
        const size_t outb = (size_t)nblk * (NKSTEP * 4096) + (size_t)s * 4096
                          + wr * 2048 + ii * 512 + lane * 8;
        #pragma unroll
        for (int j = 0; j < 8; ++j) {
            int e = s * 32 + hh * 8 + j;
            float x = (n < NN && e < EMB) ? diags[(size_t)n * EMB + e] : 0.f;
            float xs = BSCALE * x;
            _Float16 h = (_Float16)xs;
            hi[j] = h;
            lo[j] = (_Float16)(xs - (float)h);
        }
        *(f16x8*)&Bh[outb] = *(const f16x8*)hi;
        *(f16x8*)&Bl[outb] = *(const f16x8*)lo;
    }
}

// ---------------------------------------------------------------------------
// LDS-staged MFMA GEMM: 2-phase double buffer with COUNTED vmcnt (T3/T4
// minimum recipe). Per step: issue stage(s+1) -> s_waitcnt vmcnt(8) (the 8
// newer loads stay in flight across the barrier) -> raw s_barrier ->
// lane-contiguous conflict-free ds_read_b128 frags + 48 MFMA -> s_barrier.
// 128x128 tile, 4 waves (2x2), K = 320 in 10 steps. Single f32 accumulator.
// LDS: 2 x 32KB stage bufs unioned with epilogue tile -> 64KB, 2 blocks/CU.
// ---------------------------------------------------------------------------
__global__ __launch_bounds__(256, 2) void gemm_lds(
    const _Float16* __restrict__ Ah, const _Float16* __restrict__ Al,
    const _Float16* __restrict__ Bh, const _Float16* __restrict__ Bl,
    const float* __restrict__ bias, float* __restrict__ trans, int tstr) {
    __shared__ union {
        _Float16 stage[2][4][4096];   // 64 KB: [buf][Ah,Al,Bh,Bl][step tile]
        float    etile[64][132];      // 33.8 KB epilogue transpose tile
    } sh;

    const int tid  = threadIdx.x;

    // bijective chunked swizzle: XCD k owns swz in [79k, 79(k+1))
    const int bid  = blockIdx.x;
    const int swz  = (bid & 7) * 79 + (bid >> 3);
    const int vblk = swz >> 3;   // 8 consecutive swz share vblk -> A reuse in L2
    const int nblk = swz & 7;

    const int lane = tid & 63;
    const int wave = tid >> 6;
    const int wr   = wave >> 1;
    const int wc   = wave & 1;
    const int l15  = lane & 15;
    const int hh   = lane >> 4;

    const _Float16* gsrc[4] = {
        Ah + (size_t)vblk * (NKSTEP * 4096),
        Al + (size_t)vblk * (NKSTEP * 4096),
        Bh + (size_t)nblk * (NKSTEP * 4096),
        Bl + (size_t)nblk * (NKSTEP * 4096)};

    f32x4 acc[4][4] = {};

#define STAGE(buf, s)                                                        \
    _Pragma("unroll")                                                        \
    for (int L = 0; L < 8; ++L) {                                            \
        const int arr = L >> 1;                                              \
        const int off = ((L & 1) * 256 + tid) * 8;                           \
        __builtin_amdgcn_global_load_lds(                                    \
            (GUI*)(gsrc[arr] + (size_t)(s) * 4096 + off),                    \
            (LUI*)&sh.stage[buf][arr][off], 16, 0, 0);                       \
    }

    STAGE(0, 0);
    #pragma unroll 2
    for (int s = 0; s < 10; ++s) {
        const int cur = s & 1;
        if (s < 9) {
            STAGE(cur ^ 1, s + 1);
            asm volatile("s_waitcnt vmcnt(8)" ::: "memory");
        } else {
            asm volatile("s_waitcnt vmcnt(0)" ::: "memory");
        }
        __builtin_amdgcn_s_barrier();        // buf[cur] fully staged, all threads
        __builtin_amdgcn_sched_barrier(0);   // keep ds_reads below the wait

        {
            f16x8 fah[4], fal[4], fbh[4], fbl[4];
            #pragma unroll
            for (int i = 0; i < 4; ++i) {
                const int ra = wr * 2048 + i * 512 + lane * 8;   // lane-contiguous
                fah[i] = *(const f16x8*)&sh.stage[cur][0][ra];
                fal[i] = *(const f16x8*)&sh.stage[cur][1][ra];
                const int rb = wc * 2048 + i * 512 + lane * 8;
                fbh[i] = *(const f16x8*)&sh.stage[cur][2][rb];
                fbl[i] = *(const f16x8*)&sh.stage[cur][3][rb];
            }
            #pragma unroll
            for (int i = 0; i < 4; ++i)
                #pragma unroll
                for (int j = 0; j < 4; ++j) {
                    acc[i][j] = __builtin_amdgcn_mfma_f32_16x16x32_f16(fah[i], fbh[j], acc[i][j], 0, 0, 0);
                    acc[i][j] = __builtin_amdgcn_mfma_f32_16x16x32_f16(fah[i], fbl[j], acc[i][j], 0, 0, 0);
                    acc[i][j] = __builtin_amdgcn_mfma_f32_16x16x32_f16(fal[i], fbh[j], acc[i][j], 0, 0, 0);
                }
        }
        __builtin_amdgcn_s_barrier();        // reads done before buf is restaged
    }
#undef STAGE

    // ---- epilogue: LDS transpose (reuses staging LDS), float4 stores ----
    #pragma unroll 1
    for (int h = 0; h < 2; ++h) {
        __syncthreads();
        if (wr == h) {
            #pragma unroll
            for (int i = 0; i < 4; ++i)
                #pragma unroll
                for (int j = 0; j < 4; ++j)
                    #pragma unroll
                    for (int r = 0; r < 4; ++r)
                        sh.etile[i * 16 + hh * 4 + r][wc * 64 + j * 16 + l15] =
                            acc[i][j][r] * OUTSCALE;
        }
        __syncthreads();
        #pragma unroll
        for (int it = 0; it < 8; ++it) {
            const int idx = it * 256 + tid;
            const int row = idx >> 5;
            const int c4  = (idx & 31) * 4;
            const int v   = vblk * 128 + h * 64 + row;
            const int n   = nblk * 128 + c4;
            if (v < NLOC && n + 3 < NN) {
                float4 val = *(const float4*)&sh.etile[row][c4];
                const float4 b4 = *(const float4*)&bias[n];
                val.x += b4.x; val.y += b4.y; val.z += b4.z; val.w += b4.w;
                *(float4*)&trans[(size_t)v * tstr + n] = val;
            }
        }
    }
}

// ---------------------------------------------------------------------------
// Fallback fp32 GEMM (round-2 proven, stride 1000) if ws is too small.
// ---------------------------------------------------------------------------
__global__ __launch_bounds__(256) void trans_gemm(const float* __restrict__ emb,
                                                  const float* __restrict__ diags,
                                                  const float* __restrict__ bias,
                                                  float* __restrict__ trans) {
    const int tid = threadIdx.x;
    const int tn  = tid & 15;
    const int tv  = tid >> 4;
    const int v0  = blockIdx.x * 128;
    const int n0  = blockIdx.y * 128;
    __shared__ float As[15][132];
    __shared__ float Bs[15][132];
    float acc[8][8] = {};
    for (int kk = 0; kk < 20; ++kk) {
        const int e0 = kk * 15;
        #pragma unroll
        for (int l = tid; l < 480; l += 256) {
            int k = l >> 5, c = l & 31;
            int v = v0 + c * 4;
            const float* src = emb + (size_t)(e0 + k) * NLOC + v;
            float4 val;
            if (v + 3 < NLOC) val = *(const float4*)src;
            else {
                val.x = (v + 0 < NLOC) ? src[0] : 0.f;
                val.y = (v + 1 < NLOC) ? src[1] : 0.f;
                val.z = (v + 2 < NLOC) ? src[2] : 0.f;
                val.w = (v + 3 < NLOC) ? src[3] : 0.f;
            }
            *(float4*)&As[k][c * 4] = val;
        }
        for (int l = tid; l < 1920; l += 256) {
            int nn = l / 15, k = l - nn * 15;
            int n = n0 + nn;
            Bs[k][nn] = (n < NN) ? diags[n * EMB + e0 + k] : 0.f;
        }
        __syncthreads();
        #pragma unroll
        for (int k = 0; k < 15; ++k) {
            float4 a0 = *(const float4*)&As[k][tv * 4];
            float4 a1 = *(const float4*)&As[k][tv * 4 + 64];
            float4 b0 = *(const float4*)&Bs[k][tn * 4];
            float4 b1 = *(const float4*)&Bs[k][tn * 4 + 64];
            float av[8] = {a0.x, a0.y, a0.z, a0.w, a1.x, a1.y, a1.z, a1.w};
            float bv[8] = {b0.x, b0.y, b0.z, b0.w, b1.x, b1.y, b1.z, b1.w};
            #pragma unroll
            for (int i = 0; i < 8; ++i)
                #pragma unroll
                for (int j = 0; j < 8; ++j)
                    acc[i][j] += av[i] * bv[j];
        }
        __syncthreads();
    }
    #pragma unroll
    for (int i = 0; i < 8; ++i) {
        int v = v0 + (i >> 2) * 64 + tv * 4 + (i & 3);
        if (v >= NLOC) continue;
        #pragma unroll
        for (int jh = 0; jh < 2; ++jh) {
            int n = n0 + jh * 64 + tn * 4;
            if (n + 3 < NN) {
                float4 r;
                r.x = acc[i][jh * 4 + 0] + bias[n + 0];
                r.y = acc[i][jh * 4 + 1] + bias[n + 1];
                r.z = acc[i][jh * 4 + 2] + bias[n + 2];
                r.w = acc[i][jh * 4 + 3] + bias[n + 3];
                *(float4*)&trans[(size_t)v * NN + n] = r;
            } else {
                #pragma unroll
                for (int j = 0; j < 4; ++j)
                    if (n + j < NN)
                        trans[(size_t)v * NN + n + j] = acc[i][jh * 4 + j] + bias[n + j];
            }
        }
    }
}

// ---------------------------------------------------------------------------
// K2: segment-parallel max-plus scan (stride-parameterized)
// ---------------------------------------------------------------------------
__global__ __launch_bounds__(256) void scan_seg(const float* __restrict__ trans,
                                                const float* __restrict__ wildcards,
                                                const int* __restrict__ docs,
                                                const int* __restrict__ doc_lens,
                                                float* __restrict__ partial, int tstr) {
    const int b   = blockIdx.x;
    const int seg = blockIdx.y;
    const int tid = threadIdx.x;
    __shared__ int sdoc[TT];
    sdoc[tid] = docs[b * TT + tid];
    __syncthreads();

    const bool act = tid < PP;
    const int  p   = act ? tid : (PP - 1);
    const int  p5  = p * 5;
    const int  len = doc_lens[b];
    const int  t0  = seg * SEGLEN;
    const int  start = (t0 - 4 > 0) ? t0 - 4 : 0;
    const int  end   = (t0 + SEGLEN < len) ? t0 + SEGLEN : len;

    const float NI = -INFINITY;
    float score = NI;

    if (start < end) {
        const float w0 = wildcards[p5 + 0];
        const float w1 = wildcards[p5 + 1];
        const float w2 = wildcards[p5 + 2];
        const float w3 = wildcards[p5 + 3];
        const float w4 = wildcards[p5 + 4];
        const int e = (p < 50) ? 5 : (p < 100) ? 4 : (p < 150) ? 3 : 2;

        float h1 = NI, h2 = NI, h3 = NI, h4 = NI, h5 = NI;
        const int nt   = end - start;
        const int ntm1 = nt - 1;

        float A[5], B[5], C[5];
#define LOADR(R, idx) { int tt = (idx); tt = (tt < ntm1) ? tt : ntm1;          \
        const float* r_ = trans + (size_t)sdoc[start + tt] * tstr + p5;        \
        R[0] = r_[0]; R[1] = r_[1]; R[2] = r_[2]; R[3] = r_[3]; R[4] = r_[4]; }
#define STEP(R, t) { \
        float u0 = fmaxf(R[0], w0), u1 = fmaxf(R[1], w1), u2 = fmaxf(R[2], w2);\
        float u3 = fmaxf(R[3], w3), u4 = fmaxf(R[4], w4);                      \
        h5 = h4 + u4; h4 = h3 + u3; h3 = h2 + u2; h2 = h1 + u1; h1 = u0;       \
        if ((t) >= t0) {                                                       \
            float endv = (e == 5) ? h5 : (e == 4) ? h4 : (e == 3) ? h3 : h2;   \
            score = fmaxf(score, endv);                                        \
        } }

        LOADR(A, 0); LOADR(B, 1); LOADR(C, 2);
        for (int i = 0; i < nt; i += 3) {
            STEP(A, start + i);
            LOADR(A, i + 3);
            if (i + 1 < nt) { STEP(B, start + i + 1); }
            LOADR(B, i + 4);
            if (i + 2 < nt) { STEP(C, start + i + 2); }
            LOADR(C, i + 5);
        }
#undef LOADR
#undef STEP
    }

    if (act) partial[((size_t)b * NSEG + seg) * PP + p] = score;
}

// ---------------------------------------------------------------------------
// K3: finalize (unchanged, proven)
// ---------------------------------------------------------------------------
__device__ inline float block_sum_bcast(float v, volatile float* red, int tid) {
    #pragma unroll
    for (int o = 32; o > 0; o >>= 1) v += __shfl_down(v, o, 64);
    __syncthreads();
    if ((tid & 63) == 0) red[tid >> 6] = v;
    __syncthreads();
    return red[0] + red[1] + red[2] + red[3];
}

__global__ __launch_bounds__(256) void finalize(const float* __restrict__ partial,
                                                const float* __restrict__ linear_w,
                                                const float* __restrict__ linear_b,
                                                float* __restrict__ out) {
    const int b   = blockIdx.x;
    const int tid = threadIdx.x;
    __shared__ float red[4];

    const bool act = tid < PP;
    const int  p   = act ? tid : (PP - 1);

    float m = -INFINITY;
    #pragma unroll
    for (int s = 0; s < NSEG; ++s)
        m = fmaxf(m, partial[((size_t)b * NSEG + s) * PP + p]);

    float total = block_sum_bcast(act ? m : 0.f, red, tid);
    float mu = total * (1.f / (float)PP);

    int bin = (act && m > mu) ? 1 : 0;
    float c0 = bin ? linear_w[p]      : 0.f;
    float c1 = bin ? linear_w[PP + p] : 0.f;

    float r0 = block_sum_bcast(c0, red, tid);
    float r1 = block_sum_bcast(c1, red, tid);

    if (tid == 0) {
        out[b * 2 + 0] = r0 + linear_b[0];
        out[b * 2 + 1] = r1 + linear_b[1];
    }
}

// ---------------------------------------------------------------------------
extern "C" void kernel_launch(void* const* d_in, const int* in_sizes, int n_in,
                              void* d_out, int out_size, void* d_ws, size_t ws_size,
                              hipStream_t stream) {
    const float* emb    = (const float*)d_in[0];
    const float* diags  = (const float*)d_in[1];
    const float* bias   = (const float*)d_in[2];
    const float* wc     = (const float*)d_in[3];
    const float* lw     = (const float*)d_in[4];
    const float* lb     = (const float*)d_in[5];
    const int*   docs   = (const int*)d_in[6];
    const int*   dlens  = (const int*)d_in[7];
    float*       out    = (float*)d_out;

    const size_t aElems = (size_t)NVBLK * NKSTEP * 4096;  // 3,235,840
    const size_t bElems = (size_t)NNBLK * NKSTEP * 4096;  //   327,680
    const size_t partialElems = (size_t)BB * NSEG * PP;
    const size_t f16Bytes = (2 * aElems + 2 * bElems) * sizeof(_Float16);

    // choose trans stride: 1024 (line-aligned stores) > 1000 > fp32 fallback
    int tstr;
    {
        const size_t need1024 = ((size_t)NLOC * 1024 + partialElems) * 4 + f16Bytes;
        const size_t need1000 = ((size_t)NLOC * 1000 + partialElems) * 4 + f16Bytes;
        if (ws_size >= need1024)       tstr = 1024;
        else if (ws_size >= need1000)  tstr = 1000;
        else                           tstr = 0;   // fp32 fallback
    }

    float* trans   = (float*)d_ws;
    float* partial = trans + (size_t)NLOC * (tstr ? tstr : 1000);
    _Float16* Ah = (_Float16*)(partial + partialElems);
    _Float16* Al = Ah + aElems;
    _Float16* Bh = Al + aElems;
    _Float16* Bl = Bh + bElems;

    if (tstr) {
        split_ab<<<dim3(NVBLK + NNBLK, 40, 1), 128, 0, stream>>>(emb, diags, Ah, Al, Bh, Bl);
        gemm_lds<<<dim3(NVBLK * NNBLK, 1, 1), 256, 0, stream>>>(Ah, Al, Bh, Bl, bias, trans, tstr);
        scan_seg<<<dim3(BB, NSEG, 1), 256, 0, stream>>>(trans, wc, docs, dlens, partial, tstr);
    } else {
        trans_gemm<<<dim3(79, 8, 1), 256, 0, stream>>>(emb, diags, bias, trans);
        scan_seg<<<dim3(BB, NSEG, 1), 256, 0, stream>>>(trans, wc, docs, dlens, partial, 1000);
    }
    finalize<<<BB, 256, 0, stream>>>(partial, lw, lb, out);
}

// Round 12
// 68.446 us; speedup vs baseline: 1.4767x; 1.0737x over previous
//
#include <hip/hip_runtime.h>
#include <math.h>

#define EMB   300
#define NLOC  10000
#define PP    200
#define NN    1000   // PP * 5
#define BB    128
#define TT    256
#define NSEG  8
#define SEGLEN 32

#define NVBLK 79
#define NNBLK 8
#define NKSTEP 10
#define ASCALE 16.f
#define BSCALE 64.f
#define OUTSCALE (1.f / 1024.f)

typedef _Float16 f16x8 __attribute__((ext_vector_type(8)));
typedef float    f32x4 __attribute__((ext_vector_type(4)));

// ---------------------------------------------------------------------------
// Fused split kernel: fp32 -> (hi f16, lo f16), scaled so residuals stay in
// f16-normal range and all 3 partial products share ONE scale (1024 * a*b):
//   Ah = f16(16a), Al = f16(16a - Ah)     Bh = f16(64b), Bl = f16(64b - Bh)
// Lane-order tiled layout:
//   A[vblk][s(10)][wr(2)][i(4)][lane(64)][j(8)]
//     holds emb value for v = vblk*128 + wr*64 + i*16 + (lane&15),
//                       k = s*32 + (lane>>4)*8 + j.
// GEMM wave (wr,wc) fragment i is one lane-contiguous, coalesced 1KB read.
// ---------------------------------------------------------------------------
__global__ __launch_bounds__(128) void split_ab(const float* __restrict__ emb,
                                                const float* __restrict__ diags,
                                                _Float16* __restrict__ Ah,
                                                _Float16* __restrict__ Al,
                                                _Float16* __restrict__ Bh,
                                                _Float16* __restrict__ Bl) {
    const int tid  = threadIdx.x;     // wr=tid>>6, i=(tid>>4)&3, l15=tid&15
    const int bx   = blockIdx.x;
    const int kpan = blockIdx.y;      // 0..39: s = kpan>>2, hh = kpan&3
    const int s    = kpan >> 2;
    const int hh   = kpan & 3;
    const int wr   = tid >> 6;
    const int ii   = (tid >> 4) & 3;
    const int l15  = tid & 15;
    const int lane = hh * 16 + l15;
    _Float16 hi[8], lo[8];
    if (bx < NVBLK) {
        const int vblk = bx;
        const int v    = vblk * 128 + tid;
        const size_t outb = (size_t)vblk * (NKSTEP * 4096) + (size_t)s * 4096
                          + wr * 2048 + ii * 512 + lane * 8;
        #pragma unroll
        for (int j = 0; j < 8; ++j) {
            int e = s * 32 + hh * 8 + j;
            float x = (v < NLOC && e < EMB) ? emb[(size_t)e * NLOC + v] : 0.f;
            float xs = ASCALE * x;
            _Float16 h = (_Float16)xs;
            hi[j] = h;
            lo[j] = (_Float16)(xs - (float)h);
        }
        *(f16x8*)&Ah[outb] = *(const f16x8*)hi;
        *(f16x8*)&Al[outb] = *(const f16x8*)lo;
    } else {
        const int nblk = bx - NVBLK;
        const int n    = nblk * 128 + tid;
        const size_t outb = (size_t)nblk * (NKSTEP * 4096) + (size_t)s * 4096
                          + wr * 2048 + ii * 512 + lane * 8;
        #pragma unroll
        for (int j = 0; j < 8; ++j) {
            int e = s * 32 + hh * 8 + j;
            float x = (n < NN && e < EMB) ? diags[(size_t)n * EMB + e] : 0.f;
            float xs = BSCALE * x;
            _Float16 h = (_Float16)xs;
            hi[j] = h;
            lo[j] = (_Float16)(xs - (float)h);
        }
        *(f16x8*)&Bh[outb] = *(const f16x8*)hi;
        *(f16x8*)&Bl[outb] = *(const f16x8*)lo;
    }
}

// ---------------------------------------------------------------------------
// Register-direct MFMA GEMM with optional K-SPLIT x2 (doubles wave count:
// 2528 -> 5056 waves so ~3 waves/SIMD stay resident and cover load latency).
// split=1: 1264 blocks; block (vblk,nblk,half) computes K in [half*160,+160)
//          and writes fp32 partial to dst0 + half*NLOC*tstr (bias in half 0).
// split=0: 632 blocks, full K=320, single output.
// 128x128 tile, 4 waves (2x2), single f32 accumulator (shared-scale split).
// Bijective XCD-chunked swizzle; 8 consecutive blocks share one A-half-tile.
// Epilogue: LDS transpose + full-line float4 stores.
// ---------------------------------------------------------------------------
__global__ __launch_bounds__(256, 3) void gemm_reg(
    const _Float16* __restrict__ Ah, const _Float16* __restrict__ Al,
    const _Float16* __restrict__ Bh, const _Float16* __restrict__ Bl,
    const float* __restrict__ bias, float* __restrict__ dst0,
    int tstr, int split) {
    __shared__ float etile[64][132];   // 33.8 KB

    const int tid = threadIdx.x;
    const int bid = blockIdx.x;

    int vblk, nblk, half, ns;
    if (split) {
        const int swz = (bid & 7) * 158 + (bid >> 3);  // 1264 = 8*158 bijective
        nblk = swz & 7;
        half = (swz >> 3) & 1;
        vblk = swz >> 4;
        ns   = 5;
    } else {
        const int swz = (bid & 7) * 79 + (bid >> 3);   // 632 = 8*79 bijective
        nblk = swz & 7;
        half = 0;
        vblk = swz >> 3;
        ns   = 10;
    }
    float* dst = dst0 + (size_t)half * NLOC * tstr;
    const int withBias = (half == 0);

    const int lane = tid & 63;
    const int wave = tid >> 6;
    const int wr   = wave >> 1;
    const int wc   = wave & 1;
    const int l15  = lane & 15;
    const int hh   = lane >> 4;

    const size_t aoff = (size_t)vblk * (NKSTEP * 4096) + (size_t)(half * 5) * 4096
                      + wr * 2048 + lane * 8;
    const size_t boff = (size_t)nblk * (NKSTEP * 4096) + (size_t)(half * 5) * 4096
                      + wc * 2048 + lane * 8;
    const _Float16* pAh = Ah + aoff;
    const _Float16* pAl = Al + aoff;
    const _Float16* pBh = Bh + boff;
    const _Float16* pBl = Bl + boff;

    f32x4 acc[4][4] = {};

    #pragma unroll 1
    for (int s = 0; s < ns; ++s) {
        f16x8 fah[4], fal[4], fbh[4], fbl[4];
        #pragma unroll
        for (int i = 0; i < 4; ++i) {
            fah[i] = *(const f16x8*)(pAh + i * 512);
            fal[i] = *(const f16x8*)(pAl + i * 512);
            fbh[i] = *(const f16x8*)(pBh + i * 512);
            fbl[i] = *(const f16x8*)(pBl + i * 512);
        }
        #pragma unroll
        for (int i = 0; i < 4; ++i)
            #pragma unroll
            for (int j = 0; j < 4; ++j) {
                acc[i][j] = __builtin_amdgcn_mfma_f32_16x16x32_f16(fah[i], fbh[j], acc[i][j], 0, 0, 0);
                acc[i][j] = __builtin_amdgcn_mfma_f32_16x16x32_f16(fah[i], fbl[j], acc[i][j], 0, 0, 0);
                acc[i][j] = __builtin_amdgcn_mfma_f32_16x16x32_f16(fal[i], fbh[j], acc[i][j], 0, 0, 0);
            }
        pAh += 4096; pAl += 4096; pBh += 4096; pBl += 4096;
    }

    // ---- epilogue: LDS transpose, coalesced full-line float4 stores ----
    #pragma unroll 1
    for (int h = 0; h < 2; ++h) {
        __syncthreads();
        if (wr == h) {
            #pragma unroll
            for (int i = 0; i < 4; ++i)
                #pragma unroll
                for (int j = 0; j < 4; ++j)
                    #pragma unroll
                    for (int r = 0; r < 4; ++r)
                        etile[i * 16 + hh * 4 + r][wc * 64 + j * 16 + l15] =
                            acc[i][j][r] * OUTSCALE;
        }
        __syncthreads();
        #pragma unroll
        for (int it = 0; it < 8; ++it) {
            const int idx = it * 256 + tid;
            const int row = idx >> 5;
            const int c4  = (idx & 31) * 4;
            const int v   = vblk * 128 + h * 64 + row;
            const int n   = nblk * 128 + c4;
            if (v < NLOC && n + 3 < NN) {
                float4 val = *(const float4*)&etile[row][c4];
                if (withBias) {
                    const float4 b4 = *(const float4*)&bias[n];
                    val.x += b4.x; val.y += b4.y; val.z += b4.z; val.w += b4.w;
                }
                *(float4*)&dst[(size_t)v * tstr + n] = val;
            }
        }
    }
}

// ---------------------------------------------------------------------------
// Fallback fp32 GEMM (round-2 proven, stride 1000) if ws is too small.
// ---------------------------------------------------------------------------
__global__ __launch_bounds__(256) void trans_gemm(const float* __restrict__ emb,
                                                  const float* __restrict__ diags,
                                                  const float* __restrict__ bias,
                                                  float* __restrict__ trans) {
    const int tid = threadIdx.x;
    const int tn  = tid & 15;
    const int tv  = tid >> 4;
    const int v0  = blockIdx.x * 128;
    const int n0  = blockIdx.y * 128;
    __shared__ float As[15][132];
    __shared__ float Bs[15][132];
    float acc[8][8] = {};
    for (int kk = 0; kk < 20; ++kk) {
        const int e0 = kk * 15;
        #pragma unroll
        for (int l = tid; l < 480; l += 256) {
            int k = l >> 5, c = l & 31;
            int v = v0 + c * 4;
            const float* src = emb + (size_t)(e0 + k) * NLOC + v;
            float4 val;
            if (v + 3 < NLOC) val = *(const float4*)src;
            else {
                val.x = (v + 0 < NLOC) ? src[0] : 0.f;
                val.y = (v + 1 < NLOC) ? src[1] : 0.f;
                val.z = (v + 2 < NLOC) ? src[2] : 0.f;
                val.w = (v + 3 < NLOC) ? src[3] : 0.f;
            }
            *(float4*)&As[k][c * 4] = val;
        }
        for (int l = tid; l < 1920; l += 256) {
            int nn = l / 15, k = l - nn * 15;
            int n = n0 + nn;
            Bs[k][nn] = (n < NN) ? diags[n * EMB + e0 + k] : 0.f;
        }
        __syncthreads();
        #pragma unroll
        for (int k = 0; k < 15; ++k) {
            float4 a0 = *(const float4*)&As[k][tv * 4];
            float4 a1 = *(const float4*)&As[k][tv * 4 + 64];
            float4 b0 = *(const float4*)&Bs[k][tn * 4];
            float4 b1 = *(const float4*)&Bs[k][tn * 4 + 64];
            float av[8] = {a0.x, a0.y, a0.z, a0.w, a1.x, a1.y, a1.z, a1.w};
            float bv[8] = {b0.x, b0.y, b0.z, b0.w, b1.x, b1.y, b1.z, b1.w};
            #pragma unroll
            for (int i = 0; i < 8; ++i)
                #pragma unroll
                for (int j = 0; j < 8; ++j)
                    acc[i][j] += av[i] * bv[j];
        }
        __syncthreads();
    }
    #pragma unroll
    for (int i = 0; i < 8; ++i) {
        int v = v0 + (i >> 2) * 64 + tv * 4 + (i & 3);
        if (v >= NLOC) continue;
        #pragma unroll
        for (int jh = 0; jh < 2; ++jh) {
            int n = n0 + jh * 64 + tn * 4;
            if (n + 3 < NN) {
                float4 r;
                r.x = acc[i][jh * 4 + 0] + bias[n + 0];
                r.y = acc[i][jh * 4 + 1] + bias[n + 1];
                r.z = acc[i][jh * 4 + 2] + bias[n + 2];
                r.w = acc[i][jh * 4 + 3] + bias[n + 3];
                *(float4*)&trans[(size_t)v * NN + n] = r;
            } else {
                #pragma unroll
                for (int j = 0; j < 4; ++j)
                    if (n + j < NN)
                        trans[(size_t)v * NN + n + j] = acc[i][jh * 4 + j] + bias[n + j];
            }
        }
    }
}

// ---------------------------------------------------------------------------
// K2: segment-parallel max-plus scan; optionally sums two K-split partials.
// ---------------------------------------------------------------------------
__global__ __launch_bounds__(256) void scan_seg(const float* __restrict__ tr0,
                                                const float* __restrict__ tr1,
                                                int two,
                                                const float* __restrict__ wildcards,
                                                const int* __restrict__ docs,
                                                const int* __restrict__ doc_lens,
                                                float* __restrict__ partial, int tstr) {
    const int b   = blockIdx.x;
    const int seg = blockIdx.y;
    const int tid = threadIdx.x;
    __shared__ int sdoc[TT];
    sdoc[tid] = docs[b * TT + tid];
    __syncthreads();

    const bool act = tid < PP;
    const int  p   = act ? tid : (PP - 1);
    const int  p5  = p * 5;
    const int  len = doc_lens[b];
    const int  t0  = seg * SEGLEN;
    const int  start = (t0 - 4 > 0) ? t0 - 4 : 0;
    const int  end   = (t0 + SEGLEN < len) ? t0 + SEGLEN : len;

    const float NI = -INFINITY;
    float score = NI;

    if (start < end) {
        const float w0 = wildcards[p5 + 0];
        const float w1 = wildcards[p5 + 1];
        const float w2 = wildcards[p5 + 2];
        const float w3 = wildcards[p5 + 3];
        const float w4 = wildcards[p5 + 4];
        const int e = (p < 50) ? 5 : (p < 100) ? 4 : (p < 150) ? 3 : 2;

        float h1 = NI, h2 = NI, h3 = NI, h4 = NI, h5 = NI;
        const int nt   = end - start;
        const int ntm1 = nt - 1;

        float A[5], B[5], C[5];
#define LOADR(R, idx) { int tt = (idx); tt = (tt < ntm1) ? tt : ntm1;          \
        const size_t rb_ = (size_t)sdoc[start + tt] * tstr + p5;               \
        const float* r_ = tr0 + rb_;                                           \
        R[0] = r_[0]; R[1] = r_[1]; R[2] = r_[2]; R[3] = r_[3]; R[4] = r_[4];  \
        if (two) { const float* q_ = tr1 + rb_;                                \
            R[0] += q_[0]; R[1] += q_[1]; R[2] += q_[2];                       \
            R[3] += q_[3]; R[4] += q_[4]; } }
#define STEP(R, t) { \
        float u0 = fmaxf(R[0], w0), u1 = fmaxf(R[1], w1), u2 = fmaxf(R[2], w2);\
        float u3 = fmaxf(R[3], w3), u4 = fmaxf(R[4], w4);                      \
        h5 = h4 + u4; h4 = h3 + u3; h3 = h2 + u2; h2 = h1 + u1; h1 = u0;       \
        if ((t) >= t0) {                                                       \
            float endv = (e == 5) ? h5 : (e == 4) ? h4 : (e == 3) ? h3 : h2;   \
            score = fmaxf(score, endv);                                        \
        } }

        LOADR(A, 0); LOADR(B, 1); LOADR(C, 2);
        for (int i = 0; i < nt; i += 3) {
            STEP(A, start + i);
            LOADR(A, i + 3);
            if (i + 1 < nt) { STEP(B, start + i + 1); }
            LOADR(B, i + 4);
            if (i + 2 < nt) { STEP(C, start + i + 2); }
            LOADR(C, i + 5);
        }
#undef LOADR
#undef STEP
    }

    if (act) partial[((size_t)b * NSEG + seg) * PP + p] = score;
}

// ---------------------------------------------------------------------------
// K3: finalize (unchanged, proven)
// ---------------------------------------------------------------------------
__device__ inline float block_sum_bcast(float v, volatile float* red, int tid) {
    #pragma unroll
    for (int o = 32; o > 0; o >>= 1) v += __shfl_down(v, o, 64);
    __syncthreads();
    if ((tid & 63) == 0) red[tid >> 6] = v;
    __syncthreads();
    return red[0] + red[1] + red[2] + red[3];
}

__global__ __launch_bounds__(256) void finalize(const float* __restrict__ partial,
                                                const float* __restrict__ linear_w,
                                                const float* __restrict__ linear_b,
                                                float* __restrict__ out) {
    const int b   = blockIdx.x;
    const int tid = threadIdx.x;
    __shared__ float red[4];

    const bool act = tid < PP;
    const int  p   = act ? tid : (PP - 1);

    float m = -INFINITY;
    #pragma unroll
    for (int s = 0; s < NSEG; ++s)
        m = fmaxf(m, partial[((size_t)b * NSEG + s) * PP + p]);

    float total = block_sum_bcast(act ? m : 0.f, red, tid);
    float mu = total * (1.f / (float)PP);

    int bin = (act && m > mu) ? 1 : 0;
    float c0 = bin ? linear_w[p]      : 0.f;
    float c1 = bin ? linear_w[PP + p] : 0.f;

    float r0 = block_sum_bcast(c0, red, tid);
    float r1 = block_sum_bcast(c1, red, tid);

    if (tid == 0) {
        out[b * 2 + 0] = r0 + linear_b[0];
        out[b * 2 + 1] = r1 + linear_b[1];
    }
}

// ---------------------------------------------------------------------------
extern "C" void kernel_launch(void* const* d_in, const int* in_sizes, int n_in,
                              void* d_out, int out_size, void* d_ws, size_t ws_size,
                              hipStream_t stream) {
    const float* emb    = (const float*)d_in[0];
    const float* diags  = (const float*)d_in[1];
    const float* bias   = (const float*)d_in[2];
    const float* wc     = (const float*)d_in[3];
    const float* lw     = (const float*)d_in[4];
    const float* lb     = (const float*)d_in[5];
    const int*   docs   = (const int*)d_in[6];
    const int*   dlens  = (const int*)d_in[7];
    float*       out    = (float*)d_out;

    const size_t aElems = (size_t)NVBLK * NKSTEP * 4096;  // 3,235,840
    const size_t bElems = (size_t)NNBLK * NKSTEP * 4096;  //   327,680
    const size_t partialElems = (size_t)BB * NSEG * PP;
    const size_t f16Bytes = (2 * aElems + 2 * bElems) * sizeof(_Float16);

    // mode: 2 = K-split x2 @1024, 1 = unsplit @1024, 0 unsplit @1000, -1 fp32
    const size_t needSplit = ((size_t)2 * NLOC * 1024 + partialElems) * 4 + f16Bytes;
    const size_t need1024  = ((size_t)NLOC * 1024 + partialElems) * 4 + f16Bytes;
    const size_t need1000  = ((size_t)NLOC * 1000 + partialElems) * 4 + f16Bytes;
    int mode, tstr;
    if      (ws_size >= needSplit) { mode = 2;  tstr = 1024; }
    else if (ws_size >= need1024)  { mode = 1;  tstr = 1024; }
    else if (ws_size >= need1000)  { mode = 1;  tstr = 1000; }
    else                           { mode = -1; tstr = 1000; }

    float* trans0  = (float*)d_ws;
    float* trans1  = trans0 + (size_t)NLOC * tstr;          // only valid in mode 2
    float* partial = trans0 + (size_t)(mode == 2 ? 2 : 1) * NLOC * tstr;
    _Float16* Ah = (_Float16*)(partial + partialElems);
    _Float16* Al = Ah + aElems;
    _Float16* Bh = Al + aElems;
    _Float16* Bl = Bh + bElems;

    if (mode >= 1) {
        split_ab<<<dim3(NVBLK + NNBLK, 40, 1), 128, 0, stream>>>(emb, diags, Ah, Al, Bh, Bl);
        const int split = (mode == 2);
        gemm_reg<<<dim3(split ? NVBLK * NNBLK * 2 : NVBLK * NNBLK, 1, 1), 256, 0, stream>>>(
            Ah, Al, Bh, Bl, bias, trans0, tstr, split);
        scan_seg<<<dim3(BB, NSEG, 1), 256, 0, stream>>>(trans0, trans1, split, wc, docs, dlens, partial, tstr);
    } else {
        trans_gemm<<<dim3(79, 8, 1), 256, 0, stream>>>(emb, diags, bias, trans0);
        scan_seg<<<dim3(BB, NSEG, 1), 256, 0, stream>>>(trans0, trans0, 0, wc, docs, dlens, partial, 1000);
    }
    finalize<<<BB, 256, 0, stream>>>(partial, lw, lb, out);
}

// Round 13
// 54.979 us; speedup vs baseline: 1.8384x; 1.2449x over previous
//
#include <hip/hip_runtime.h>
#include <math.h>

#define EMB   300
#define NLOC  10000
#define PP    200
#define NN    1000   // PP * 5
#define BB    128
#define TT    256
#define NSEG  8
#define SEGLEN 32

#define NVBLK 79
#define NNBLK 8
#define NKPAN 40
#define ASCALE 16.f
#define BSCALE 64.f
#define OUTSCALE (1.f / 1024.f)

typedef _Float16 f16x8 __attribute__((ext_vector_type(8)));
typedef float    f32x4 __attribute__((ext_vector_type(4)));

// ---------------------------------------------------------------------------
// Fused split kernel: fp32 -> (hi f16, lo f16), scaled so residuals stay in
// f16-normal range and all 3 partial products share ONE scale (1024 * a*b):
//   Ah = f16(16a), Al = f16(16a - Ah)   (emb ~ N(0,1))
//   Bh = f16(64b), Bl = f16(64b - Bh)   (diags ~ 0.05*N(0,1))
// Layout: A_tiled[vblk][kpan][m(128)][j(8)], B_tiled[nblk][kpan][n(128)][j(8)]
// so fragment reads are contiguous 16B per lane.
// ---------------------------------------------------------------------------
__global__ __launch_bounds__(128) void split_ab(const float* __restrict__ emb,
                                                const float* __restrict__ diags,
                                                _Float16* __restrict__ Ah,
                                                _Float16* __restrict__ Al,
                                                _Float16* __restrict__ Bh,
                                                _Float16* __restrict__ Bl) {
    const int m    = threadIdx.x;
    const int bx   = blockIdx.x;
    const int kpan = blockIdx.y;
    _Float16 hi[8], lo[8];
    if (bx < NVBLK) {
        const int vblk = bx;
        const int v    = vblk * 128 + m;
        const size_t outb = ((size_t)(vblk * NKPAN + kpan) * 128 + m) * 8;
        #pragma unroll
        for (int j = 0; j < 8; ++j) {
            int e = kpan * 8 + j;
            float x = (v < NLOC && e < EMB) ? emb[(size_t)e * NLOC + v] : 0.f;
            float xs = ASCALE * x;
            _Float16 h = (_Float16)xs;
            hi[j] = h;
            lo[j] = (_Float16)(xs - (float)h);
        }
        *(f16x8*)&Ah[outb] = *(const f16x8*)hi;
        *(f16x8*)&Al[outb] = *(const f16x8*)lo;
    } else {
        const int nblk = bx - NVBLK;
        const int n    = nblk * 128 + m;
        const size_t outb = ((size_t)(nblk * NKPAN + kpan) * 128 + m) * 8;
        #pragma unroll
        for (int j = 0; j < 8; ++j) {
            int e = kpan * 8 + j;
            float x = (n < NN && e < EMB) ? diags[(size_t)n * EMB + e] : 0.f;
            float xs = BSCALE * x;
            _Float16 h = (_Float16)xs;
            hi[j] = h;
            lo[j] = (_Float16)(xs - (float)h);
        }
        *(f16x8*)&Bh[outb] = *(const f16x8*)hi;
        *(f16x8*)&Bl[outb] = *(const f16x8*)lo;
    }
}

// ---------------------------------------------------------------------------
// Register-direct MFMA GEMM, single accumulator, 2-deep fragment double
// buffer with SCHED_BARRIER pinning: all 16 loads of step s+1 are forced to
// ISSUE before step s's MFMAs (sched_barrier(0) fence), so the compiler must
// emit a counted vmcnt wait instead of sinking each load to its consumer.
// 128x128 block tile, 4 waves (2x2), wave = 4x4 tiles of 16x16x32 f16,
// K = 320 in 10 steps. XCD-chunked swizzle (632 = 8*79). Epilogue: LDS
// transpose + full-line float4 stores with bias + exact /1024 rescale.
// ---------------------------------------------------------------------------
__global__ __launch_bounds__(256, 2) void gemm_s1(
    const _Float16* __restrict__ Ah, const _Float16* __restrict__ Al,
    const _Float16* __restrict__ Bh, const _Float16* __restrict__ Bl,
    const float* __restrict__ bias, float* __restrict__ trans, int tstr) {
    const int tid  = threadIdx.x;

    // bijective chunked swizzle: XCD k owns swz in [79k, 79(k+1))
    const int bid  = blockIdx.x;
    const int swz  = (bid & 7) * 79 + (bid >> 3);
    const int vblk = swz >> 3;   // 8 consecutive swz share vblk -> A reuse in L2
    const int nblk = swz & 7;

    const int lane = tid & 63;
    const int wave = tid >> 6;
    const int wr   = wave >> 1;
    const int wc   = wave & 1;
    const int l15  = lane & 15;
    const int hh   = lane >> 4;  // 8-wide k-panel within the 32-wide k-step

    const size_t aoff = (size_t)vblk * (NKPAN * 1024) + (size_t)hh * 1024 + (size_t)(wr * 64 + l15) * 8;
    const size_t boff = (size_t)nblk * (NKPAN * 1024) + (size_t)hh * 1024 + (size_t)(wc * 64 + l15) * 8;
    const _Float16* pAh = Ah + aoff;
    const _Float16* pAl = Al + aoff;
    const _Float16* pBh = Bh + boff;
    const _Float16* pBl = Bl + boff;

    f32x4 acc[4][4] = {};

    f16x8 A0[4], L0[4], B0[4], M0[4];
    f16x8 A1[4], L1[4], B1[4], M1[4];

#define LOADSET(Aa, La, Bb, Mm, s)                                   \
    _Pragma("unroll")                                                \
    for (int i = 0; i < 4; ++i) {                                    \
        Aa[i] = *(const f16x8*)(pAh + (s) * 4096 + i * 128);         \
        La[i] = *(const f16x8*)(pAl + (s) * 4096 + i * 128);         \
        Bb[i] = *(const f16x8*)(pBh + (s) * 4096 + i * 128);         \
        Mm[i] = *(const f16x8*)(pBl + (s) * 4096 + i * 128);         \
    }

#define MFMASET(Aa, La, Bb, Mm)                                                              \
    _Pragma("unroll")                                                                        \
    for (int i = 0; i < 4; ++i)                                                              \
        _Pragma("unroll")                                                                    \
        for (int j = 0; j < 4; ++j) {                                                        \
            acc[i][j] = __builtin_amdgcn_mfma_f32_16x16x32_f16(Aa[i], Bb[j], acc[i][j], 0, 0, 0); \
            acc[i][j] = __builtin_amdgcn_mfma_f32_16x16x32_f16(Aa[i], Mm[j], acc[i][j], 0, 0, 0); \
            acc[i][j] = __builtin_amdgcn_mfma_f32_16x16x32_f16(La[i], Bb[j], acc[i][j], 0, 0, 0); \
        }

    LOADSET(A0, L0, B0, M0, 0);
    #pragma unroll
    for (int ss = 0; ss < 5; ++ss) {
        LOADSET(A1, L1, B1, M1, 2 * ss + 1);     // prefetch odd step
        __builtin_amdgcn_sched_barrier(0);       // pin: loads issue BEFORE MFMAs
        MFMASET(A0, L0, B0, M0);                 // compute even step
        if (ss < 4) LOADSET(A0, L0, B0, M0, 2 * ss + 2);  // prefetch next even
        __builtin_amdgcn_sched_barrier(0);       // pin again
        MFMASET(A1, L1, B1, M1);                 // compute odd step
    }
#undef LOADSET
#undef MFMASET

    // ---- epilogue: LDS transpose, coalesced full-line float4 stores ----
    __shared__ float etile[64][132];   // 33.8 KB

    #pragma unroll 1
    for (int h = 0; h < 2; ++h) {
        __syncthreads();
        if (wr == h) {
            #pragma unroll
            for (int i = 0; i < 4; ++i)
                #pragma unroll
                for (int j = 0; j < 4; ++j)
                    #pragma unroll
                    for (int r = 0; r < 4; ++r)
                        etile[i * 16 + hh * 4 + r][wc * 64 + j * 16 + l15] =
                            acc[i][j][r] * OUTSCALE;
        }
        __syncthreads();
        // 64 rows x 128 floats = 2048 float4; 8 per thread
        #pragma unroll
        for (int it = 0; it < 8; ++it) {
            const int idx = it * 256 + tid;
            const int row = idx >> 5;
            const int c4  = (idx & 31) * 4;
            const int v   = vblk * 128 + h * 64 + row;
            const int n   = nblk * 128 + c4;
            if (v < NLOC && n + 3 < NN) {
                float4 val = *(const float4*)&etile[row][c4];
                const float4 b4 = *(const float4*)&bias[n];
                val.x += b4.x; val.y += b4.y; val.z += b4.z; val.w += b4.w;
                *(float4*)&trans[(size_t)v * tstr + n] = val;
            }
        }
    }
}

// ---------------------------------------------------------------------------
// Fallback fp32 GEMM (round-2 proven, stride 1000) if ws is too small.
// ---------------------------------------------------------------------------
__global__ __launch_bounds__(256) void trans_gemm(const float* __restrict__ emb,
                                                  const float* __restrict__ diags,
                                                  const float* __restrict__ bias,
                                                  float* __restrict__ trans) {
    const int tid = threadIdx.x;
    const int tn  = tid & 15;
    const int tv  = tid >> 4;
    const int v0  = blockIdx.x * 128;
    const int n0  = blockIdx.y * 128;
    __shared__ float As[15][132];
    __shared__ float Bs[15][132];
    float acc[8][8] = {};
    for (int kk = 0; kk < 20; ++kk) {
        const int e0 = kk * 15;
        #pragma unroll
        for (int l = tid; l < 480; l += 256) {
            int k = l >> 5, c = l & 31;
            int v = v0 + c * 4;
            const float* src = emb + (size_t)(e0 + k) * NLOC + v;
            float4 val;
            if (v + 3 < NLOC) val = *(const float4*)src;
            else {
                val.x = (v + 0 < NLOC) ? src[0] : 0.f;
                val.y = (v + 1 < NLOC) ? src[1] : 0.f;
                val.z = (v + 2 < NLOC) ? src[2] : 0.f;
                val.w = (v + 3 < NLOC) ? src[3] : 0.f;
            }
            *(float4*)&As[k][c * 4] = val;
        }
        for (int l = tid; l < 1920; l += 256) {
            int nn = l / 15, k = l - nn * 15;
            int n = n0 + nn;
            Bs[k][nn] = (n < NN) ? diags[n * EMB + e0 + k] : 0.f;
        }
        __syncthreads();
        #pragma unroll
        for (int k = 0; k < 15; ++k) {
            float4 a0 = *(const float4*)&As[k][tv * 4];
            float4 a1 = *(const float4*)&As[k][tv * 4 + 64];
            float4 b0 = *(const float4*)&Bs[k][tn * 4];
            float4 b1 = *(const float4*)&Bs[k][tn * 4 + 64];
            float av[8] = {a0.x, a0.y, a0.z, a0.w, a1.x, a1.y, a1.z, a1.w};
            float bv[8] = {b0.x, b0.y, b0.z, b0.w, b1.x, b1.y, b1.z, b1.w};
            #pragma unroll
            for (int i = 0; i < 8; ++i)
                #pragma unroll
                for (int j = 0; j < 8; ++j)
                    acc[i][j] += av[i] * bv[j];
        }
        __syncthreads();
    }
    #pragma unroll
    for (int i = 0; i < 8; ++i) {
        int v = v0 + (i >> 2) * 64 + tv * 4 + (i & 3);
        if (v >= NLOC) continue;
        #pragma unroll
        for (int jh = 0; jh < 2; ++jh) {
            int n = n0 + jh * 64 + tn * 4;
            if (n + 3 < NN) {
                float4 r;
                r.x = acc[i][jh * 4 + 0] + bias[n + 0];
                r.y = acc[i][jh * 4 + 1] + bias[n + 1];
                r.z = acc[i][jh * 4 + 2] + bias[n + 2];
                r.w = acc[i][jh * 4 + 3] + bias[n + 3];
                *(float4*)&trans[(size_t)v * NN + n] = r;
            } else {
                #pragma unroll
                for (int j = 0; j < 4; ++j)
                    if (n + j < NN)
                        trans[(size_t)v * NN + n + j] = acc[i][jh * 4 + j] + bias[n + j];
            }
        }
    }
}

// ---------------------------------------------------------------------------
// K2: segment-parallel max-plus scan (stride-parameterized)
// ---------------------------------------------------------------------------
__global__ __launch_bounds__(256) void scan_seg(const float* __restrict__ trans,
                                                const float* __restrict__ wildcards,
                                                const int* __restrict__ docs,
                                                const int* __restrict__ doc_lens,
                                                float* __restrict__ partial, int tstr) {
    const int b   = blockIdx.x;
    const int seg = blockIdx.y;
    const int tid = threadIdx.x;
    __shared__ int sdoc[TT];
    sdoc[tid] = docs[b * TT + tid];
    __syncthreads();

    const bool act = tid < PP;
    const int  p   = act ? tid : (PP - 1);
    const int  p5  = p * 5;
    const int  len = doc_lens[b];
    const int  t0  = seg * SEGLEN;
    const int  start = (t0 - 4 > 0) ? t0 - 4 : 0;
    const int  end   = (t0 + SEGLEN < len) ? t0 + SEGLEN : len;

    const float NI = -INFINITY;
    float score = NI;

    if (start < end) {
        const float w0 = wildcards[p5 + 0];
        const float w1 = wildcards[p5 + 1];
        const float w2 = wildcards[p5 + 2];
        const float w3 = wildcards[p5 + 3];
        const float w4 = wildcards[p5 + 4];
        const int e = (p < 50) ? 5 : (p < 100) ? 4 : (p < 150) ? 3 : 2;

        float h1 = NI, h2 = NI, h3 = NI, h4 = NI, h5 = NI;
        const int nt   = end - start;
        const int ntm1 = nt - 1;

        float A[5], B[5], C[5];
#define LOADR(R, idx) { int tt = (idx); tt = (tt < ntm1) ? tt : ntm1;          \
        const float* r_ = trans + (size_t)sdoc[start + tt] * tstr + p5;        \
        R[0] = r_[0]; R[1] = r_[1]; R[2] = r_[2]; R[3] = r_[3]; R[4] = r_[4]; }
#define STEP(R, t) { \
        float u0 = fmaxf(R[0], w0), u1 = fmaxf(R[1], w1), u2 = fmaxf(R[2], w2);\
        float u3 = fmaxf(R[3], w3), u4 = fmaxf(R[4], w4);                      \
        h5 = h4 + u4; h4 = h3 + u3; h3 = h2 + u2; h2 = h1 + u1; h1 = u0;       \
        if ((t) >= t0) {                                                       \
            float endv = (e == 5) ? h5 : (e == 4) ? h4 : (e == 3) ? h3 : h2;   \
            score = fmaxf(score, endv);                                        \
        } }

        LOADR(A, 0); LOADR(B, 1); LOADR(C, 2);
        for (int i = 0; i < nt; i += 3) {
            STEP(A, start + i);
            LOADR(A, i + 3);
            if (i + 1 < nt) { STEP(B, start + i + 1); }
            LOADR(B, i + 4);
            if (i + 2 < nt) { STEP(C, start + i + 2); }
            LOADR(C, i + 5);
        }
#undef LOADR
#undef STEP
    }

    if (act) partial[((size_t)b * NSEG + seg) * PP + p] = score;
}

// ---------------------------------------------------------------------------
// K3: finalize (unchanged, proven)
// ---------------------------------------------------------------------------
__device__ inline float block_sum_bcast(float v, volatile float* red, int tid) {
    #pragma unroll
    for (int o = 32; o > 0; o >>= 1) v += __shfl_down(v, o, 64);
    __syncthreads();
    if ((tid & 63) == 0) red[tid >> 6] = v;
    __syncthreads();
    return red[0] + red[1] + red[2] + red[3];
}

__global__ __launch_bounds__(256) void finalize(const float* __restrict__ partial,
                                                const float* __restrict__ linear_w,
                                                const float* __restrict__ linear_b,
                                                float* __restrict__ out) {
    const int b   = blockIdx.x;
    const int tid = threadIdx.x;
    __shared__ float red[4];

    const bool act = tid < PP;
    const int  p   = act ? tid : (PP - 1);

    float m = -INFINITY;
    #pragma unroll
    for (int s = 0; s < NSEG; ++s)
        m = fmaxf(m, partial[((size_t)b * NSEG + s) * PP + p]);

    float total = block_sum_bcast(act ? m : 0.f, red, tid);
    float mu = total * (1.f / (float)PP);

    int bin = (act && m > mu) ? 1 : 0;
    float c0 = bin ? linear_w[p]      : 0.f;
    float c1 = bin ? linear_w[PP + p] : 0.f;

    float r0 = block_sum_bcast(c0, red, tid);
    float r1 = block_sum_bcast(c1, red, tid);

    if (tid == 0) {
        out[b * 2 + 0] = r0 + linear_b[0];
        out[b * 2 + 1] = r1 + linear_b[1];
    }
}

// ---------------------------------------------------------------------------
extern "C" void kernel_launch(void* const* d_in, const int* in_sizes, int n_in,
                              void* d_out, int out_size, void* d_ws, size_t ws_size,
                              hipStream_t stream) {
    const float* emb    = (const float*)d_in[0];
    const float* diags  = (const float*)d_in[1];
    const float* bias   = (const float*)d_in[2];
    const float* wc     = (const float*)d_in[3];
    const float* lw     = (const float*)d_in[4];
    const float* lb     = (const float*)d_in[5];
    const int*   docs   = (const int*)d_in[6];
    const int*   dlens  = (const int*)d_in[7];
    float*       out    = (float*)d_out;

    const size_t aElems = (size_t)NVBLK * NKPAN * 128 * 8;  // 3,235,840
    const size_t bElems = (size_t)NNBLK * NKPAN * 128 * 8;  //   327,680
    const size_t partialElems = (size_t)BB * NSEG * PP;
    const size_t f16Bytes = (2 * aElems + 2 * bElems) * sizeof(_Float16);

    // choose trans stride: 1024 (line-aligned stores) > 1000 > fp32 fallback
    int tstr;
    {
        const size_t need1024 = ((size_t)NLOC * 1024 + partialElems) * 4 + f16Bytes;
        const size_t need1000 = ((size_t)NLOC * 1000 + partialElems) * 4 + f16Bytes;
        if (ws_size >= need1024)       tstr = 1024;
        else if (ws_size >= need1000)  tstr = 1000;
        else                           tstr = 0;   // fp32 fallback
    }

    float* trans   = (float*)d_ws;
    float* partial = trans + (size_t)NLOC * (tstr ? tstr : 1000);
    _Float16* Ah = (_Float16*)(partial + partialElems);
    _Float16* Al = Ah + aElems;
    _Float16* Bh = Al + aElems;
    _Float16* Bl = Bh + bElems;

    if (tstr) {
        split_ab<<<dim3(NVBLK + NNBLK, NKPAN, 1), 128, 0, stream>>>(emb, diags, Ah, Al, Bh, Bl);
        gemm_s1<<<dim3(NVBLK * NNBLK, 1, 1), 256, 0, stream>>>(Ah, Al, Bh, Bl, bias, trans, tstr);
        scan_seg<<<dim3(BB, NSEG, 1), 256, 0, stream>>>(trans, wc, docs, dlens, partial, tstr);
    } else {
        trans_gemm<<<dim3(79, 8, 1), 256, 0, stream>>>(emb, diags, bias, trans);
        scan_seg<<<dim3(BB, NSEG, 1), 256, 0, stream>>>(trans, wc, docs, dlens, partial, 1000);
    }
    finalize<<<BB, 256, 0, stream>>>(partial, lw, lb, out);
}